// Round 9
// baseline (513.680 us; speedup 1.0000x reference)
//
#include <hip/hip_runtime.h>
#include <hip/hip_bf16.h>
#include <math.h>

// RelationAwareTreeLSTMCell on gfx950 — fp32 in/out.
// B=4096 N=32 H=256 DIN=256 R=3.
// Round 12: r7's pass count (1024 W_f passes) at 2 blocks/CU.
//   Evidence: r7 is outstanding-load limited (Little's law: 8 waves/CU, ~16
//   loads/thread in flight -> 2.8 TB/s ceiling = measured), phases serialize
//   at 1 block/CU. r8's NBC=8 spilled (WRITE +68 MB) — reverted.
//   Design: MB=8, NBC=4, grid 512, 2 chunks: passes = grid*chunks = 1024
//   (invariant vs r7), LDS forced to ~78.5 KB (< half of 160 KB pool) by
//   moving csL to the out buffer (r8-verified trick: partial c -> out[B+b],
//   read back after barrier, same CU, L2-coherent). waves_per_eu(4,4) = 128
//   VGPR cap, proven sufficient for this inner loop by r7.
// fused_main: 512 blocks x 512 thr, 2 chunks of NBC=4 batches, 2 blocks/CU.
//   Per chunk: barrier -> stage child_h (fused attn dot, 8 its) -> barrier ->
//   per-wave softmax (2 pairs/lane) -> hsum (2 passes) ->
//   rid-masked MFMA GEMM (M=256,N=128,K=3x256) -> direct-cc epilogue -> out.
//   Then gate GEMM (8 x 512)@(512 x 768) (rows duplicated, q<2 stores)
//   + fused sigmoid/tanh -> fp32 out.

#define B_    4096
#define N_    32
#define H_    256
#define DIN_  256
#define R_    3
#define MB    8
#define NBC   4
#define CHUNKS (MB / NBC)
#define DECAY 0.7f

// ws layout (bf16 elements)
#define WS_WF   0
#define WS_WI   196608
#define WS_WO   327680
#define WS_WU   458752
#define WS_ELEMS 589824                       // * 2 B = 1,179,648 B needed

typedef __bf16 bf16;
typedef bf16  bf16x8 __attribute__((ext_vector_type(8)));
typedef float f32x4  __attribute__((ext_vector_type(4)));

__device__ __forceinline__ float sigmoidf_(float x) { return 1.0f / (1.0f + __expf(-x)); }

__device__ __forceinline__ bf16x8 cvt8_nt(const float* p) {
    f32x4 a = __builtin_nontemporal_load((const f32x4*)p);
    f32x4 b = __builtin_nontemporal_load((const f32x4*)(p + 4));
    bf16x8 r;
    #pragma unroll
    for (int j = 0; j < 4; ++j) { r[j] = (bf16)a[j]; r[j + 4] = (bf16)b[j]; }
    return r;
}
__device__ __forceinline__ bf16x8 cvt8_c(const float* p) {
    f32x4 a = *(const f32x4*)p;
    f32x4 b = *(const f32x4*)(p + 4);
    bf16x8 r;
    #pragma unroll
    for (int j = 0; j < 4; ++j) { r[j] = (bf16)a[j]; r[j + 4] = (bf16)b[j]; }
    return r;
}

template<bool WSW>
__device__ __forceinline__ bf16x8 ldw8(const bf16* wsp, const float* fp, int idx) {
    if constexpr (WSW) return *(const bf16x8*)(wsp + idx);
    else               return cvt8_c(fp + idx);
}

// ---- weight prep: fp32 -> bf16 into d_ws. 288 blocks x 256 thr, exact cover. ----
__global__ __launch_bounds__(256) void wprep(
    const float* __restrict__ Wf, const float* __restrict__ Wi,
    const float* __restrict__ Wo, const float* __restrict__ Wu,
    bf16* __restrict__ ws)
{
    int i = (blockIdx.x * 256 + threadIdx.x) * 8;
    const float* src; int off;
    if      (i < WS_WI) { src = Wf; off = i - WS_WF; }
    else if (i < WS_WO) { src = Wi; off = i - WS_WI; }
    else if (i < WS_WU) { src = Wo; off = i - WS_WO; }
    else                { src = Wu; off = i - WS_WU; }
    *(bf16x8*)(ws + i) = cvt8_c(src + off);
}

template<bool WSW>
__global__ __launch_bounds__(512) __attribute__((amdgpu_waves_per_eu(4, 4)))
void fused_main(
    const float* __restrict__ ivec,
    const float* __restrict__ child_h, const float* __restrict__ child_c,
    const int*  __restrict__ rel_ids,  const void* __restrict__ vmaskp,
    const float* __restrict__ rel_emb,
    const float* __restrict__ W_i, const float* __restrict__ b_i,
    const float* __restrict__ W_f, const float* __restrict__ b_f,
    const float* __restrict__ W_o, const float* __restrict__ b_o,
    const float* __restrict__ W_u, const float* __restrict__ b_u,
    const float* __restrict__ w_att, const float* __restrict__ b_att,
    const bf16* __restrict__ ws, float* __restrict__ out)
{
    __shared__ __align__(16) bf16 chs[NBC][N_][264];   // 67584 B
    __shared__ __align__(16) bf16 hsumL[MB][264];      //  4224 B
    __shared__ float watt[H_];                         //  1024 B
    __shared__ float bfl[R_][H_];                      //  3072 B
    __shared__ float dall[MB][N_];                     //  1024 B
    __shared__ int   rids[MB][N_];                     //  1024 B
    __shared__ float scoreT[NBC * N_];                 //   512 B
    __shared__ float rdotL[4];
    __shared__ int   m8flag;
    // total ~78.5 KB -> 2 blocks/CU

    const int tid  = threadIdx.x;
    const int wave = tid >> 6;
    const int lane = tid & 63;
    const int t    = lane & 15;
    const int q    = lane >> 4;
    const int b0   = blockIdx.x * MB;

    const bf16* wfb = ws + WS_WF;
    const bf16* wib = ws + WS_WI;
    const bf16* wob = ws + WS_WO;
    const bf16* wub = ws + WS_WU;

    // ---- mask-format probe (wave 0): byte-bools have nonzero "upper bytes" ----
    if (tid < 64) {
        const unsigned char* vb = (const unsigned char*)vmaskp;
        int bad = vb[tid * 4 + 1] | vb[tid * 4 + 2] | vb[tid * 4 + 3];
        unsigned long long any = __ballot(bad != 0);
        if (tid == 0) m8flag = (any != 0ull) ? 1 : 0;
    }
    __syncthreads();

    // ---- small tables ----
    if (tid < 256) {                       // H_ == MB*N_ == 256
        watt[tid] = w_att[tid];
        int idx = b0 * N_ + tid;
        rids[tid >> 5][tid & 31] = rel_ids[idx];
        bool vm = m8flag ? (((const unsigned char*)vmaskp)[idx] != 0)
                         : (((const int*)vmaskp)[idx] != 0);
        dall[tid >> 5][tid & 31] = vm ? DECAY : 1.0f;
    }
    for (int i = tid; i < R_ * H_; i += 512) ((float*)bfl)[i] = b_f[i];
    if (tid == 0) rdotL[3] = b_att[0];
    __syncthreads();

    // rdot[r] = dot(rel_emb[r], w_att); published by chunk-0's barriers
    if (wave < R_) {
        int r = wave;
        float p = 0.f;
        #pragma unroll
        for (int j = 0; j < 4; ++j) {
            int h = lane * 4 + j;
            p += rel_emb[r * H_ + h] * watt[h];
        }
        #pragma unroll
        for (int off = 32; off >= 1; off >>= 1) p += __shfl_xor(p, off);
        if (lane == 0) rdotL[r] = p;
    }

    // ================= chunk loop: NBC=4 batches each =================
    for (int ck = 0; ck < CHUNKS; ++ck) {
        __syncthreads();     // chs/scoreT free (prev chunk's reads done)

        // ---- stage child_h (nt fp32 -> bf16 LDS) with FUSED attention dot ----
        // 8 its x 512 thr x 8 elems = 4 batches x 32 rows x 256.
        {
            size_t base = (size_t)(b0 + ck * NBC) * (N_ * H_);
            float dp[8];
            #pragma unroll
            for (int it = 0; it < 8; ++it) {
                int ge = (it * 512 + tid) << 3;          // 0..32760
                int row = ge >> 8;                       // 0..127 (= bi*32+n)
                int h = ge & 255;
                f32x4 a = __builtin_nontemporal_load((const f32x4*)(child_h + base + ge));
                f32x4 b = __builtin_nontemporal_load((const f32x4*)(child_h + base + ge + 4));
                bf16x8 r; float p = 0.f;
                #pragma unroll
                for (int j = 0; j < 4; ++j) {
                    r[j] = (bf16)a[j]; r[j + 4] = (bf16)b[j];
                    p += a[j] * watt[h + j] + b[j] * watt[h + 4 + j];
                }
                *(bf16x8*)(&chs[row >> 5][row & 31][h]) = r;
                dp[it] = p;
            }
            #pragma unroll
            for (int off = 16; off >= 1; off >>= 1) {
                #pragma unroll
                for (int it = 0; it < 8; ++it) dp[it] += __shfl_xor(dp[it], off);
            }
            if ((tid & 31) == 0) {
                int grp = tid >> 5;                      // 0..15
                #pragma unroll
                for (int it = 0; it < 8; ++it) scoreT[it * 16 + grp] = dp[it];
            }
        }
        __syncthreads();

        // ---- per-wave softmax: 128 (bi,n) pairs, 2 per lane, in regs ----
        float att0, att1;   // att*decay for (bi=lane>>5, n) and (bi=2+lane>>5, n)
        {
            int n  = lane & 31;
            int bi = lane >> 5;
            int bl0 = ck * NBC + bi, bl1 = bl0 + 2;
            float d0 = dall[bl0][n], d1 = dall[bl1][n];
            float s0 = d0 * scoreT[lane]      + rdotL[rids[bl0][n]] + rdotL[3];
            float s1 = d1 * scoreT[64 + lane] + rdotL[rids[bl1][n]] + rdotL[3];
            float m0 = s0, m1 = s1;
            #pragma unroll
            for (int off = 16; off >= 1; off >>= 1) {
                m0 = fmaxf(m0, __shfl_xor(m0, off));
                m1 = fmaxf(m1, __shfl_xor(m1, off));
            }
            float e0 = __expf(s0 - m0), e1 = __expf(s1 - m1);
            float u0 = e0, u1 = e1;
            #pragma unroll
            for (int off = 16; off >= 1; off >>= 1) {
                u0 += __shfl_xor(u0, off);
                u1 += __shfl_xor(u1, off);
            }
            att0 = (e0 / u0) * d0;
            att1 = (e1 / u1) * d1;
        }

        // ---- h_sum -> LDS (2 passes; attn via shfl broadcast) ----
        #pragma unroll
        for (int ps = 0; ps < 2; ++ps) {
            int bi = (tid >> 8) + ps * 2;
            int g  = tid & 255;
            int bl = ck * NBC + bi;
            float s = 0.f;
            #pragma unroll 8
            for (int n = 0; n < N_; ++n) {
                float av = __shfl(ps ? att1 : att0, ((tid >> 8) << 5) | n);
                s += av * (float)chs[bi][n][g];
            }
            hsumL[bl][g] = (bf16)s;
        }

        // ---- rid-masked MFMA GEMM: Q[g,n] (M=256, N=128, K=3x256) ----
        f32x4 acc[2][8];
        #pragma unroll
        for (int i = 0; i < 2; ++i)
            #pragma unroll
            for (int j = 0; j < 8; ++j)
                #pragma unroll
                for (int c = 0; c < 4; ++c) acc[i][j][c] = 0.0f;

        bf16x8 bzero;
        #pragma unroll
        for (int i = 0; i < 8; ++i) bzero[i] = (bf16)0.0f;

        int myrid[8];
        #pragma unroll
        for (int nt = 0; nt < 8; ++nt)
            myrid[nt] = rids[ck * NBC + (nt >> 1)][((nt & 1) << 4) + t];

        #pragma unroll
        for (int kc = 0; kc < 8; ++kc) {
            const int k = kc * 32 + q * 8;
            bf16x8 v[8];
            #pragma unroll
            for (int nt = 0; nt < 8; ++nt)
                v[nt] = *(const bf16x8*)(&chs[nt >> 1][((nt & 1) << 4) + t][k]);
            #pragma unroll
            for (int r = 0; r < R_; ++r) {
                bf16x8 afrag[2];
                #pragma unroll
                for (int m2 = 0; m2 < 2; ++m2) {
                    int g = (wave * 2 + m2) * 16 + t;
                    afrag[m2] = ldw8<WSW>(wfb, W_f, (r * H_ + g) * H_ + k);
                }
                #pragma unroll
                for (int nt = 0; nt < 8; ++nt) {
                    bf16x8 vm = (myrid[nt] == r) ? v[nt] : bzero;
                    acc[0][nt] = __builtin_amdgcn_mfma_f32_16x16x32_bf16(afrag[0], vm, acc[0][nt], 0, 0, 0);
                    acc[1][nt] = __builtin_amdgcn_mfma_f32_16x16x32_bf16(afrag[1], vm, acc[1][nt], 0, 0, 0);
                }
            }
        }

        // ---- cs epilogue: direct child_c loads; partial c -> out[B+b] ----
        // cs[bl][g] = sum_n cc*d*(d*Q + b_f[rid]); 4-lane q-groups cover 64 B rows.
        {
            f32x4 cc[2][4][2];   // [m2][bi][j]
            #pragma unroll
            for (int m2 = 0; m2 < 2; ++m2)
                #pragma unroll
                for (int bi = 0; bi < NBC; ++bi) {
                    size_t cbase = (size_t)(b0 + ck * NBC + bi) * (N_ * H_);
                    #pragma unroll
                    for (int j = 0; j < 2; ++j)
                        cc[m2][bi][j] = __builtin_nontemporal_load(
                            (const f32x4*)(child_c + cbase + (size_t)(((j << 4) + t)) * H_
                                           + (wave * 2 + m2) * 16 + q * 4));
                }
            #pragma unroll
            for (int m2 = 0; m2 < 2; ++m2) {
                #pragma unroll
                for (int reg = 0; reg < 4; ++reg) {
                    const int g = (wave * 2 + m2) * 16 + q * 4 + reg;
                    #pragma unroll
                    for (int bi = 0; bi < NBC; ++bi) {
                        int bl = ck * NBC + bi;
                        float p = 0.f;
                        #pragma unroll
                        for (int j = 0; j < 2; ++j) {
                            int nt = bi * 2 + j;
                            int n  = (j << 4) + t;
                            float d = dall[bl][n];
                            p += cc[m2][bi][j][reg] * d
                                 * fmaf(d, acc[m2][nt][reg], bfl[rids[bl][n]][g]);
                        }
                        p += __shfl_xor(p, 1);
                        p += __shfl_xor(p, 2);
                        p += __shfl_xor(p, 4);
                        p += __shfl_xor(p, 8);
                        if (t == 0)
                            out[(size_t)B_ * H_ + (size_t)(b0 + bl) * H_ + g] = p;
                    }
                }
            }
        }
    }
    __syncthreads();   // drains vmcnt: cs partials visible block-wide via L2

    // ============ gates: (8 x 512) @ (512 x 768), batch rows duplicated ============
    const int j0 = wave * 32;
    const int tt = t & 7;                 // MB=8: rows 8..15 duplicate rows 0..7
    f32x4 accI[2], accO[2], accU[2];
    #pragma unroll
    for (int c = 0; c < 2; ++c)
        #pragma unroll
        for (int r = 0; r < 4; ++r) { accI[c][r] = 0.f; accO[c][r] = 0.f; accU[c][r] = 0.f; }

    #pragma unroll
    for (int kc = 0; kc < 16; ++kc) {
        const int k = kc * 32 + q * 8;
        bf16x8 a;
        if (kc < 8) a = cvt8_nt(ivec + (size_t)(b0 + tt) * DIN_ + k);
        else        a = *(const bf16x8*)(&hsumL[tt][k - 256]);
        #pragma unroll
        for (int c = 0; c < 2; ++c) {
            int j = j0 + c * 16 + t;
            bf16x8 bI = ldw8<WSW>(wib, W_i, j * 512 + k);
            bf16x8 bO = ldw8<WSW>(wob, W_o, j * 512 + k);
            bf16x8 bU = ldw8<WSW>(wub, W_u, j * 512 + k);
            accI[c] = __builtin_amdgcn_mfma_f32_16x16x32_bf16(a, bI, accI[c], 0, 0, 0);
            accO[c] = __builtin_amdgcn_mfma_f32_16x16x32_bf16(a, bO, accO[c], 0, 0, 0);
            accU[c] = __builtin_amdgcn_mfma_f32_16x16x32_bf16(a, bU, accU[c], 0, 0, 0);
        }
    }

    if (q < 2) {                          // C rows q*4+reg in 0..7 are the real batches
        #pragma unroll
        for (int c = 0; c < 2; ++c) {
            const int j = j0 + c * 16 + t;
            float biv = b_i[j], bov = b_o[j], buv = b_u[j];
            #pragma unroll
            for (int reg = 0; reg < 4; ++reg) {
                int bl = q * 4 + reg;
                size_t o1 = (size_t)(b0 + bl) * H_ + j;
                size_t o2 = (size_t)B_ * H_ + o1;
                float csv = out[o2];               // partial c from cs epilogue
                float iv = sigmoidf_(accI[c][reg] + biv);
                float ov = sigmoidf_(accO[c][reg] + bov);
                float uv = tanhf(accU[c][reg] + buv);
                float cv = fmaf(iv, uv, csv);
                float hv = ov * tanhf(cv);
                __builtin_nontemporal_store(hv, out + o1);
                __builtin_nontemporal_store(cv, out + o2);
            }
        }
    }
}

extern "C" void kernel_launch(void* const* d_in, const int* in_sizes, int n_in,
                              void* d_out, int out_size, void* d_ws, size_t ws_size,
                              hipStream_t stream)
{
    const float* ivec    = (const float*)d_in[0];
    const float* child_h = (const float*)d_in[1];
    const float* child_c = (const float*)d_in[2];
    const int*   relids  = (const int*)d_in[3];
    const void*  vmask   = d_in[4];
    const float* rel_emb = (const float*)d_in[5];
    const float* W_i     = (const float*)d_in[6];
    const float* b_i     = (const float*)d_in[7];
    const float* W_f     = (const float*)d_in[8];
    const float* b_f     = (const float*)d_in[9];
    const float* W_o     = (const float*)d_in[10];
    const float* b_o     = (const float*)d_in[11];
    const float* W_u     = (const float*)d_in[12];
    const float* b_u     = (const float*)d_in[13];
    const float* w_att   = (const float*)d_in[14];
    const float* b_att   = (const float*)d_in[15];
    float* out = (float*)d_out;
    bf16*  ws  = (bf16*)d_ws;

    const bool wsw = (ws_size >= (size_t)WS_ELEMS * sizeof(bf16));

    if (wsw) {
        hipLaunchKernelGGL(wprep, dim3(WS_ELEMS / 8 / 256), dim3(256), 0, stream,
                           W_f, W_i, W_o, W_u, ws);
        hipLaunchKernelGGL((fused_main<true>), dim3(B_ / MB), dim3(512), 0, stream,
                           ivec, child_h, child_c, relids, vmask, rel_emb,
                           W_i, b_i, W_f, b_f, W_o, b_o, W_u, b_u, w_att, b_att,
                           ws, out);
    } else {
        hipLaunchKernelGGL((fused_main<false>), dim3(B_ / MB), dim3(512), 0, stream,
                           ivec, child_h, child_c, relids, vmask, rel_emb,
                           W_i, b_i, W_f, b_f, W_o, b_o, W_u, b_u, w_att, b_att,
                           ws, out);
    }
}

// Round 10
// 420.793 us; speedup vs baseline: 1.2207x; 1.2207x over previous
//
#include <hip/hip_runtime.h>
#include <hip/hip_bf16.h>
#include <math.h>

// RelationAwareTreeLSTMCell on gfx950 — fp32 in/out.
// B=4096 N=32 H=256 DIN=256 R=3.
// Round 13: r7 (201us anchor: MB=16, NBC=4, grid 256, waves_per_eu(2,2))
//   with ONE change: cs epilogue software-pipelined per-bi.
//   Evidence: r7's WRITE=79 MB vs ~9.6 MB true writes -> ~70 MB scratch
//   round-trips. Pressure peak = cc[2][4][2] (64 VGPR) live against full
//   acc (64, AGPR) in the cs epilogue. r9 proved NBC=4 can't fit a 128-reg
//   budget (2 blocks/CU impossible), so the fix is to lower the peak at the
//   256-reg point: load cc per-bi (16 regs), prefetch bi+1 while consuming
//   bi (cA/cB ping-pong, fully static indexing). Peak cc-live 64 -> 32.
// fused_main: 256 blocks x 512 thr, 4 chunks of NBC=4 batches, LDS ~101 KB.
//   Per chunk: barrier -> stage child_h (fused attn dot) -> barrier ->
//   per-wave softmax (2 pairs/lane) -> hsum (2 passes) ->
//   rid-masked MFMA GEMM (M=256,N=128,K=3x256) -> per-bi cs epilogue.
//   Then gate GEMM (16 x 512)@(512 x 768) + fused sigmoid/tanh -> fp32 out.

#define B_    4096
#define N_    32
#define H_    256
#define DIN_  256
#define R_    3
#define MB    16
#define NBC   4
#define CHUNKS (MB / NBC)
#define DECAY 0.7f

// ws layout (bf16 elements)
#define WS_WF   0
#define WS_WI   196608
#define WS_WO   327680
#define WS_WU   458752
#define WS_ELEMS 589824                       // * 2 B = 1,179,648 B needed

typedef __bf16 bf16;
typedef bf16  bf16x8 __attribute__((ext_vector_type(8)));
typedef float f32x4  __attribute__((ext_vector_type(4)));

__device__ __forceinline__ float sigmoidf_(float x) { return 1.0f / (1.0f + __expf(-x)); }

__device__ __forceinline__ bf16x8 cvt8_nt(const float* p) {
    f32x4 a = __builtin_nontemporal_load((const f32x4*)p);
    f32x4 b = __builtin_nontemporal_load((const f32x4*)(p + 4));
    bf16x8 r;
    #pragma unroll
    for (int j = 0; j < 4; ++j) { r[j] = (bf16)a[j]; r[j + 4] = (bf16)b[j]; }
    return r;
}
__device__ __forceinline__ bf16x8 cvt8_c(const float* p) {
    f32x4 a = *(const f32x4*)p;
    f32x4 b = *(const f32x4*)(p + 4);
    bf16x8 r;
    #pragma unroll
    for (int j = 0; j < 4; ++j) { r[j] = (bf16)a[j]; r[j + 4] = (bf16)b[j]; }
    return r;
}

template<bool WSW>
__device__ __forceinline__ bf16x8 ldw8(const bf16* wsp, const float* fp, int idx) {
    if constexpr (WSW) return *(const bf16x8*)(wsp + idx);
    else               return cvt8_c(fp + idx);
}

// ---- weight prep: fp32 -> bf16 into d_ws. 288 blocks x 256 thr, exact cover. ----
__global__ __launch_bounds__(256) void wprep(
    const float* __restrict__ Wf, const float* __restrict__ Wi,
    const float* __restrict__ Wo, const float* __restrict__ Wu,
    bf16* __restrict__ ws)
{
    int i = (blockIdx.x * 256 + threadIdx.x) * 8;
    const float* src; int off;
    if      (i < WS_WI) { src = Wf; off = i - WS_WF; }
    else if (i < WS_WO) { src = Wi; off = i - WS_WI; }
    else if (i < WS_WU) { src = Wo; off = i - WS_WO; }
    else                { src = Wu; off = i - WS_WU; }
    *(bf16x8*)(ws + i) = cvt8_c(src + off);
}

template<bool WSW>
__global__ __launch_bounds__(512) __attribute__((amdgpu_waves_per_eu(2, 2)))
void fused_main(
    const float* __restrict__ ivec,
    const float* __restrict__ child_h, const float* __restrict__ child_c,
    const int*  __restrict__ rel_ids,  const void* __restrict__ vmaskp,
    const float* __restrict__ rel_emb,
    const float* __restrict__ W_i, const float* __restrict__ b_i,
    const float* __restrict__ W_f, const float* __restrict__ b_f,
    const float* __restrict__ W_o, const float* __restrict__ b_o,
    const float* __restrict__ W_u, const float* __restrict__ b_u,
    const float* __restrict__ w_att, const float* __restrict__ b_att,
    const bf16* __restrict__ ws, float* __restrict__ out)
{
    __shared__ __align__(16) bf16 chs[NBC][N_][264];   // 67584 B
    __shared__ __align__(16) bf16 hsumL[MB][264];      //  8448 B
    __shared__ float csL[MB][H_];                      // 16384 B
    __shared__ float watt[H_];                         //  1024 B
    __shared__ float bfl[R_][H_];                      //  3072 B
    __shared__ float dall[MB][N_];                     //  2048 B
    __shared__ int   rids[MB][N_];                     //  2048 B
    __shared__ float scoreT[NBC * N_];                 //   512 B
    __shared__ float rdotL[4];
    __shared__ int   m8flag;

    const int tid  = threadIdx.x;
    const int wave = tid >> 6;
    const int lane = tid & 63;
    const int t    = lane & 15;
    const int q    = lane >> 4;
    const int b0   = blockIdx.x * MB;

    const bf16* wfb = ws + WS_WF;
    const bf16* wib = ws + WS_WI;
    const bf16* wob = ws + WS_WO;
    const bf16* wub = ws + WS_WU;

    // ---- mask-format probe (wave 0): byte-bools have nonzero "upper bytes" ----
    if (tid < 64) {
        const unsigned char* vb = (const unsigned char*)vmaskp;
        int bad = vb[tid * 4 + 1] | vb[tid * 4 + 2] | vb[tid * 4 + 3];
        unsigned long long any = __ballot(bad != 0);
        if (tid == 0) m8flag = (any != 0ull) ? 1 : 0;
    }
    __syncthreads();

    // ---- small tables ----
    if (tid < H_) watt[tid] = w_att[tid];
    {
        int idx = b0 * N_ + tid;           // MB*N_ == 512 == blockDim
        rids[tid >> 5][tid & 31] = rel_ids[idx];
        bool vm = m8flag ? (((const unsigned char*)vmaskp)[idx] != 0)
                         : (((const int*)vmaskp)[idx] != 0);
        dall[tid >> 5][tid & 31] = vm ? DECAY : 1.0f;
    }
    for (int i = tid; i < R_ * H_; i += 512) ((float*)bfl)[i] = b_f[i];
    if (tid == 0) rdotL[3] = b_att[0];
    __syncthreads();

    // rdot[r] = dot(rel_emb[r], w_att); published by chunk-0's barriers
    if (wave < R_) {
        int r = wave;
        float p = 0.f;
        #pragma unroll
        for (int j = 0; j < 4; ++j) {
            int h = lane * 4 + j;
            p += rel_emb[r * H_ + h] * watt[h];
        }
        #pragma unroll
        for (int off = 32; off >= 1; off >>= 1) p += __shfl_xor(p, off);
        if (lane == 0) rdotL[r] = p;
    }

    // ================= chunk loop: NBC=4 batches each =================
    for (int ck = 0; ck < CHUNKS; ++ck) {
        __syncthreads();     // chs/scoreT free (prev chunk's reads done)

        // ---- stage child_h (nt fp32 -> bf16 LDS) with FUSED attention dot ----
        // 8 its x 512 thr x 8 elems = 4 batches x 32 rows x 256.
        {
            size_t base = (size_t)(b0 + ck * NBC) * (N_ * H_);
            float dp[8];
            #pragma unroll
            for (int it = 0; it < 8; ++it) {
                int ge = (it * 512 + tid) << 3;          // 0..32760
                int row = ge >> 8;                       // 0..127 (= bi*32+n)
                int h = ge & 255;
                f32x4 a = __builtin_nontemporal_load((const f32x4*)(child_h + base + ge));
                f32x4 b = __builtin_nontemporal_load((const f32x4*)(child_h + base + ge + 4));
                bf16x8 r; float p = 0.f;
                #pragma unroll
                for (int j = 0; j < 4; ++j) {
                    r[j] = (bf16)a[j]; r[j + 4] = (bf16)b[j];
                    p += a[j] * watt[h + j] + b[j] * watt[h + 4 + j];
                }
                *(bf16x8*)(&chs[row >> 5][row & 31][h]) = r;
                dp[it] = p;
            }
            #pragma unroll
            for (int off = 16; off >= 1; off >>= 1) {
                #pragma unroll
                for (int it = 0; it < 8; ++it) dp[it] += __shfl_xor(dp[it], off);
            }
            if ((tid & 31) == 0) {
                int grp = tid >> 5;                      // 0..15
                #pragma unroll
                for (int it = 0; it < 8; ++it) scoreT[it * 16 + grp] = dp[it];
            }
        }
        __syncthreads();

        // ---- per-wave softmax: 128 (bi,n) pairs, 2 per lane, in regs ----
        float att0, att1;   // att*decay for (bi=lane>>5, n) and (bi=2+lane>>5, n)
        {
            int n  = lane & 31;
            int bi = lane >> 5;
            int bl0 = ck * NBC + bi, bl1 = bl0 + 2;
            float d0 = dall[bl0][n], d1 = dall[bl1][n];
            float s0 = d0 * scoreT[lane]      + rdotL[rids[bl0][n]] + rdotL[3];
            float s1 = d1 * scoreT[64 + lane] + rdotL[rids[bl1][n]] + rdotL[3];
            float m0 = s0, m1 = s1;
            #pragma unroll
            for (int off = 16; off >= 1; off >>= 1) {
                m0 = fmaxf(m0, __shfl_xor(m0, off));
                m1 = fmaxf(m1, __shfl_xor(m1, off));
            }
            float e0 = __expf(s0 - m0), e1 = __expf(s1 - m1);
            float u0 = e0, u1 = e1;
            #pragma unroll
            for (int off = 16; off >= 1; off >>= 1) {
                u0 += __shfl_xor(u0, off);
                u1 += __shfl_xor(u1, off);
            }
            att0 = (e0 / u0) * d0;
            att1 = (e1 / u1) * d1;
        }

        // ---- h_sum -> LDS (2 passes; attn via shfl broadcast) ----
        #pragma unroll
        for (int ps = 0; ps < 2; ++ps) {
            int bi = (tid >> 8) + ps * 2;
            int g  = tid & 255;
            int bl = ck * NBC + bi;
            float s = 0.f;
            #pragma unroll 8
            for (int n = 0; n < N_; ++n) {
                float av = __shfl(ps ? att1 : att0, ((tid >> 8) << 5) | n);
                s += av * (float)chs[bi][n][g];
            }
            hsumL[bl][g] = (bf16)s;
        }

        // ---- rid-masked MFMA GEMM: Q[g,n] (M=256, N=128, K=3x256) ----
        f32x4 acc[2][8];
        #pragma unroll
        for (int i = 0; i < 2; ++i)
            #pragma unroll
            for (int j = 0; j < 8; ++j)
                #pragma unroll
                for (int c = 0; c < 4; ++c) acc[i][j][c] = 0.0f;

        bf16x8 bzero;
        #pragma unroll
        for (int i = 0; i < 8; ++i) bzero[i] = (bf16)0.0f;

        int myrid[8];
        #pragma unroll
        for (int nt = 0; nt < 8; ++nt)
            myrid[nt] = rids[ck * NBC + (nt >> 1)][((nt & 1) << 4) + t];

        #pragma unroll
        for (int kc = 0; kc < 8; ++kc) {
            const int k = kc * 32 + q * 8;
            bf16x8 v[8];
            #pragma unroll
            for (int nt = 0; nt < 8; ++nt)
                v[nt] = *(const bf16x8*)(&chs[nt >> 1][((nt & 1) << 4) + t][k]);
            #pragma unroll
            for (int r = 0; r < R_; ++r) {
                bf16x8 afrag[2];
                #pragma unroll
                for (int m2 = 0; m2 < 2; ++m2) {
                    int g = (wave * 2 + m2) * 16 + t;
                    afrag[m2] = ldw8<WSW>(wfb, W_f, (r * H_ + g) * H_ + k);
                }
                #pragma unroll
                for (int nt = 0; nt < 8; ++nt) {
                    bf16x8 vm = (myrid[nt] == r) ? v[nt] : bzero;
                    acc[0][nt] = __builtin_amdgcn_mfma_f32_16x16x32_bf16(afrag[0], vm, acc[0][nt], 0, 0, 0);
                    acc[1][nt] = __builtin_amdgcn_mfma_f32_16x16x32_bf16(afrag[1], vm, acc[1][nt], 0, 0, 0);
                }
            }
        }

        // ---- cs epilogue: per-bi software pipeline (peak cc-live 64 -> 32) ----
        // cs[bl][g] = sum_n cc*d*(d*Q + b_f[rid]); cA = current bi, cB = next.
        {
            f32x4 cA[2][2], cB[2][2];   // [m2][j]
            {
                size_t cbase = (size_t)(b0 + ck * NBC) * (N_ * H_);
                #pragma unroll
                for (int m2 = 0; m2 < 2; ++m2)
                    #pragma unroll
                    for (int j = 0; j < 2; ++j)
                        cA[m2][j] = __builtin_nontemporal_load(
                            (const f32x4*)(child_c + cbase + (size_t)(((j << 4) + t)) * H_
                                           + (wave * 2 + m2) * 16 + q * 4));
            }
            #pragma unroll
            for (int bi = 0; bi < NBC; ++bi) {
                if (bi + 1 < NBC) {
                    size_t cbase = (size_t)(b0 + ck * NBC + bi + 1) * (N_ * H_);
                    #pragma unroll
                    for (int m2 = 0; m2 < 2; ++m2)
                        #pragma unroll
                        for (int j = 0; j < 2; ++j)
                            cB[m2][j] = __builtin_nontemporal_load(
                                (const f32x4*)(child_c + cbase + (size_t)(((j << 4) + t)) * H_
                                               + (wave * 2 + m2) * 16 + q * 4));
                }
                const int bl = ck * NBC + bi;
                #pragma unroll
                for (int m2 = 0; m2 < 2; ++m2) {
                    #pragma unroll
                    for (int reg = 0; reg < 4; ++reg) {
                        const int g = (wave * 2 + m2) * 16 + q * 4 + reg;
                        float p = 0.f;
                        #pragma unroll
                        for (int j = 0; j < 2; ++j) {
                            int nt = bi * 2 + j;
                            int n  = (j << 4) + t;
                            float d = dall[bl][n];
                            p += cA[m2][j][reg] * d
                                 * fmaf(d, acc[m2][nt][reg], bfl[rids[bl][n]][g]);
                        }
                        p += __shfl_xor(p, 1);
                        p += __shfl_xor(p, 2);
                        p += __shfl_xor(p, 4);
                        p += __shfl_xor(p, 8);
                        if (t == 0) csL[bl][g] = p;
                    }
                }
                if (bi + 1 < NBC) {
                    #pragma unroll
                    for (int m2 = 0; m2 < 2; ++m2)
                        #pragma unroll
                        for (int j = 0; j < 2; ++j)
                            cA[m2][j] = cB[m2][j];
                }
            }
        }
    }
    __syncthreads();

    // ============ gates: (16 x 512) @ (512 x 768), fused epilogue ============
    const int j0 = wave * 32;
    f32x4 accI[2], accO[2], accU[2];
    #pragma unroll
    for (int c = 0; c < 2; ++c)
        #pragma unroll
        for (int r = 0; r < 4; ++r) { accI[c][r] = 0.f; accO[c][r] = 0.f; accU[c][r] = 0.f; }

    #pragma unroll
    for (int kc = 0; kc < 16; ++kc) {
        const int k = kc * 32 + q * 8;
        bf16x8 a;
        if (kc < 8) a = cvt8_nt(ivec + (size_t)(b0 + t) * DIN_ + k);
        else        a = *(const bf16x8*)(&hsumL[t][k - 256]);
        #pragma unroll
        for (int c = 0; c < 2; ++c) {
            int j = j0 + c * 16 + t;
            bf16x8 bI = ldw8<WSW>(wib, W_i, j * 512 + k);
            bf16x8 bO = ldw8<WSW>(wob, W_o, j * 512 + k);
            bf16x8 bU = ldw8<WSW>(wub, W_u, j * 512 + k);
            accI[c] = __builtin_amdgcn_mfma_f32_16x16x32_bf16(a, bI, accI[c], 0, 0, 0);
            accO[c] = __builtin_amdgcn_mfma_f32_16x16x32_bf16(a, bO, accO[c], 0, 0, 0);
            accU[c] = __builtin_amdgcn_mfma_f32_16x16x32_bf16(a, bU, accU[c], 0, 0, 0);
        }
    }

    #pragma unroll
    for (int c = 0; c < 2; ++c) {
        const int j = j0 + c * 16 + t;
        float biv = b_i[j], bov = b_o[j], buv = b_u[j];
        #pragma unroll
        for (int reg = 0; reg < 4; ++reg) {
            int bl = q * 4 + reg;
            size_t o1 = (size_t)(b0 + bl) * H_ + j;
            size_t o2 = (size_t)B_ * H_ + o1;
            float iv = sigmoidf_(accI[c][reg] + biv);
            float ov = sigmoidf_(accO[c][reg] + bov);
            float uv = tanhf(accU[c][reg] + buv);
            float cv = fmaf(iv, uv, csL[bl][j]);
            float hv = ov * tanhf(cv);
            __builtin_nontemporal_store(hv, out + o1);
            __builtin_nontemporal_store(cv, out + o2);
        }
    }
}

extern "C" void kernel_launch(void* const* d_in, const int* in_sizes, int n_in,
                              void* d_out, int out_size, void* d_ws, size_t ws_size,
                              hipStream_t stream)
{
    const float* ivec    = (const float*)d_in[0];
    const float* child_h = (const float*)d_in[1];
    const float* child_c = (const float*)d_in[2];
    const int*   relids  = (const int*)d_in[3];
    const void*  vmask   = d_in[4];
    const float* rel_emb = (const float*)d_in[5];
    const float* W_i     = (const float*)d_in[6];
    const float* b_i     = (const float*)d_in[7];
    const float* W_f     = (const float*)d_in[8];
    const float* b_f     = (const float*)d_in[9];
    const float* W_o     = (const float*)d_in[10];
    const float* b_o     = (const float*)d_in[11];
    const float* W_u     = (const float*)d_in[12];
    const float* b_u     = (const float*)d_in[13];
    const float* w_att   = (const float*)d_in[14];
    const float* b_att   = (const float*)d_in[15];
    float* out = (float*)d_out;
    bf16*  ws  = (bf16*)d_ws;

    const bool wsw = (ws_size >= (size_t)WS_ELEMS * sizeof(bf16));

    if (wsw) {
        hipLaunchKernelGGL(wprep, dim3(WS_ELEMS / 8 / 256), dim3(256), 0, stream,
                           W_f, W_i, W_o, W_u, ws);
        hipLaunchKernelGGL((fused_main<true>), dim3(B_ / MB), dim3(512), 0, stream,
                           ivec, child_h, child_c, relids, vmask, rel_emb,
                           W_i, b_i, W_f, b_f, W_o, b_o, W_u, b_u, w_att, b_att,
                           ws, out);
    } else {
        hipLaunchKernelGGL((fused_main<false>), dim3(B_ / MB), dim3(512), 0, stream,
                           ivec, child_h, child_c, relids, vmask, rel_emb,
                           W_i, b_i, W_f, b_f, W_o, b_o, W_u, b_u, w_att, b_att,
                           ws, out);
    }
}